// Round 1
// baseline (125.645 us; speedup 1.0000x reference)
//
#include <hip/hip_runtime.h>
#include <math.h>

// One block (256 threads) per 32x32 image. Thread t owns 4 consecutive
// pixels: row = t/8, cols = (t%8)*4 .. +3  (float4 coalesced load/store).
// LDS: 34x35 zero-bordered tile (stride 35 -> ~2 lanes/bank, conflict-free
// per m136). Two block reductions (conv min/max, sharpened min/max) via
// wave64 shfl_xor butterfly + 8-float LDS combine.

#define LDS_STRIDE 35

__global__ __launch_bounds__(256) void laplacian_fwd_kernel(
    const float* __restrict__ in,      // (16384, 1, 32, 32)
    const float* __restrict__ weight,  // (1, 9)
    const float* __restrict__ wfac,    // (1, 1)
    float* __restrict__ out)           // (1, 16384, 1, 32, 32)
{
    __shared__ float img[34 * LDS_STRIDE];
    __shared__ float red[8];

    const int b = blockIdx.x;
    const int t = threadIdx.x;
    const float* src = in + (size_t)b * 1024;
    float* dst = out + (size_t)b * 1024;

    // Kernel coefficients: ker = clip(w, -0.999, 0.999) * clip(wf, 1.001, 254.999)
    const float wf = fminf(fmaxf(wfac[0], 1.001f), 254.999f);
    float k[9];
#pragma unroll
    for (int i = 0; i < 9; ++i)
        k[i] = fminf(fmaxf(weight[i], -0.999f), 0.999f) * wf;

    // Zero the whole tile (establishes the zero-padding border).
    for (int i = t; i < 34 * LDS_STRIDE; i += 256) img[i] = 0.0f;
    __syncthreads();

    const int row  = t >> 3;        // 0..31
    const int col0 = (t & 7) << 2;  // 0,4,...,28
    const float4 x4 = *(const float4*)(src + row * 32 + col0);
    {
        float* wp = &img[(row + 1) * LDS_STRIDE + (col0 + 1)];
        wp[0] = x4.x; wp[1] = x4.y; wp[2] = x4.z; wp[3] = x4.w;
    }
    __syncthreads();

    // 3x3 cross-correlation, zero padding (borders are zeros in LDS).
    float conv[4];
#pragma unroll
    for (int j = 0; j < 4; ++j) {
        const float* p = &img[row * LDS_STRIDE + col0 + j];  // (row-1, col-1) in image coords
        float s;
        s  = k[0] * p[0] + k[1] * p[1] + k[2] * p[2];
        p += LDS_STRIDE;
        s += k[3] * p[0] + k[4] * p[1] + k[5] * p[2];
        p += LDS_STRIDE;
        s += k[6] * p[0] + k[7] * p[1] + k[8] * p[2];
        conv[j] = s;
    }

    const int wave = t >> 6;
    const int lane = t & 63;

    // ---- reduction 1: min/max of conv over the image ----
    float mn = fminf(fminf(conv[0], conv[1]), fminf(conv[2], conv[3]));
    float mx = fmaxf(fmaxf(conv[0], conv[1]), fmaxf(conv[2], conv[3]));
#pragma unroll
    for (int m = 1; m < 64; m <<= 1) {
        mn = fminf(mn, __shfl_xor(mn, m, 64));
        mx = fmaxf(mx, __shfl_xor(mx, m, 64));
    }
    if (lane == 0) { red[wave] = mn; red[4 + wave] = mx; }
    __syncthreads();
    const float cmin = fminf(fminf(red[0], red[1]), fminf(red[2], red[3]));
    const float cmax = fmaxf(fmaxf(red[4], red[5]), fmaxf(red[6], red[7]));
    __syncthreads();  // red reused below

    // mod = (conv - cmin) / max(cmax - cmin, 1e-6) * 255 ; sharpened = x + mod
    const float cden = fmaxf(cmax - cmin, 1e-6f);
    const float xv[4] = {x4.x, x4.y, x4.z, x4.w};
    float sh[4];
#pragma unroll
    for (int j = 0; j < 4; ++j)
        sh[j] = xv[j] + (conv[j] - cmin) / cden * 255.0f;

    // ---- reduction 2: min/max of sharpened over the image ----
    mn = fminf(fminf(sh[0], sh[1]), fminf(sh[2], sh[3]));
    mx = fmaxf(fmaxf(sh[0], sh[1]), fmaxf(sh[2], sh[3]));
#pragma unroll
    for (int m = 1; m < 64; m <<= 1) {
        mn = fminf(mn, __shfl_xor(mn, m, 64));
        mx = fmaxf(mx, __shfl_xor(mx, m, 64));
    }
    if (lane == 0) { red[wave] = mn; red[4 + wave] = mx; }
    __syncthreads();
    const float smin = fminf(fminf(red[0], red[1]), fminf(red[2], red[3]));
    const float smax = fmaxf(fmaxf(red[4], red[5]), fmaxf(red[6], red[7]));

    // res = floor(clip((sh - smin) / clip(smax - smin, 1e-6, 255) * 255, 0, 255))
    const float sden = fminf(fmaxf(smax - smin, 1e-6f), 255.0f);
    float4 o;
    o.x = floorf(fminf(fmaxf((sh[0] - smin) / sden * 255.0f, 0.0f), 255.0f));
    o.y = floorf(fminf(fmaxf((sh[1] - smin) / sden * 255.0f, 0.0f), 255.0f));
    o.z = floorf(fminf(fmaxf((sh[2] - smin) / sden * 255.0f, 0.0f), 255.0f));
    o.w = floorf(fminf(fmaxf((sh[3] - smin) / sden * 255.0f, 0.0f), 255.0f));
    *(float4*)(dst + row * 32 + col0) = o;
}

extern "C" void kernel_launch(void* const* d_in, const int* in_sizes, int n_in,
                              void* d_out, int out_size, void* d_ws, size_t ws_size,
                              hipStream_t stream) {
    const float* in   = (const float*)d_in[0];  // (16384,1,32,32)
    const float* w    = (const float*)d_in[1];  // (1,9)
    const float* wfac = (const float*)d_in[2];  // (1,1)
    float* out = (float*)d_out;                 // (1,16384,1,32,32)
    const int B = in_sizes[0] / 1024;           // 16384
    laplacian_fwd_kernel<<<B, 256, 0, stream>>>(in, w, wfac, out);
}

// Round 2
// 124.335 us; speedup vs baseline: 1.0105x; 1.0105x over previous
//
#include <hip/hip_runtime.h>
#include <math.h>

// One block (256 threads) per 32x32 image. Thread t owns 4 consecutive
// pixels: row = t/8, cols = (t%8)*4 .. +3.
// LDS tile: 34 rows x stride 40; image col c lives at LDS col c+4 so the
// conv-center 4-float read is 16B aligned (ds_read_b128). Borders (image
// row/col -1 and 32) are zeroed explicitly (144 cells, <=1 write/thread).
// Block-wide min/max via ds_swizzle xor-butterfly (immediate patterns, no
// per-step VALU addr math) within 32-lane halves + 8-slot LDS combine.
// Divisions hoisted to 2 block-uniform precise divs (inv = 255/den).

#define S 40  // LDS row stride in floats

template <int P>
__device__ __forceinline__ float swz(float v) {
    return __int_as_float(__builtin_amdgcn_ds_swizzle(__float_as_int(v), P));
}

__device__ __forceinline__ void butterfly32(float& mn, float& mx) {
    mn = fminf(mn, swz<0x041F>(mn)); mx = fmaxf(mx, swz<0x041F>(mx)); // xor 1
    mn = fminf(mn, swz<0x081F>(mn)); mx = fmaxf(mx, swz<0x081F>(mx)); // xor 2
    mn = fminf(mn, swz<0x101F>(mn)); mx = fmaxf(mx, swz<0x101F>(mx)); // xor 4
    mn = fminf(mn, swz<0x201F>(mn)); mx = fmaxf(mx, swz<0x201F>(mx)); // xor 8
    mn = fminf(mn, swz<0x401F>(mn)); mx = fmaxf(mx, swz<0x401F>(mx)); // xor 16
}

__global__ __launch_bounds__(256) void laplacian_fwd_kernel(
    const float* __restrict__ in,      // (16384, 1, 32, 32)
    const float* __restrict__ weight,  // (1, 9)
    const float* __restrict__ wfac,    // (1, 1)
    float* __restrict__ out)           // (1, 16384, 1, 32, 32)
{
    __shared__ float img[34 * S];
    __shared__ float redA[16];
    __shared__ float redB[16];

    const int b = blockIdx.x;
    const int t = threadIdx.x;
    const float* src = in + (size_t)b * 1024;
    float* dst = out + (size_t)b * 1024;

    const int row  = t >> 3;        // 0..31
    const int col0 = (t & 7) << 2;  // 0,4,...,28

    // Issue the global load early to overlap with border zeroing / weights.
    const float4 x4 = *(const float4*)(src + row * 32 + col0);

    // Border zeros: image rows -1,32 (LDS rows 0,33; zero full 40-wide rows)
    // and image cols -1,32 (LDS cols 3,36) for rows 1..32.
    if (t < 40)       img[t] = 0.0f;
    else if (t < 80)  img[33 * S + (t - 40)] = 0.0f;
    else if (t < 112) img[(t - 79) * S + 3]  = 0.0f;
    else if (t < 144) img[(t - 111) * S + 36] = 0.0f;

    // Kernel coefficients (block-uniform).
    const float wf = fminf(fmaxf(wfac[0], 1.001f), 254.999f);
    float k[9];
#pragma unroll
    for (int i = 0; i < 9; ++i)
        k[i] = fminf(fmaxf(weight[i], -0.999f), 0.999f) * wf;

    *(float4*)&img[(row + 1) * S + (col0 + 4)] = x4;
    __syncthreads();

    // 3x3 cross-correlation. Per input row: 1 aligned float4 (ds_read_b128)
    // + 2 scalars (ds_read2_b32-able).
    float conv[4] = {0.0f, 0.0f, 0.0f, 0.0f};
#pragma unroll
    for (int r = 0; r < 3; ++r) {
        const float* p = &img[(row + r) * S + col0];
        const float  l  = p[3];                      // image col c0-1
        const float4 m  = *(const float4*)(p + 4);   // image cols c0..c0+3
        const float  rr = p[8];                      // image col c0+4
        const float k0 = k[3 * r], k1 = k[3 * r + 1], k2 = k[3 * r + 2];
        conv[0] += k0 * l   + k1 * m.x + k2 * m.y;
        conv[1] += k0 * m.x + k1 * m.y + k2 * m.z;
        conv[2] += k0 * m.y + k1 * m.z + k2 * m.w;
        conv[3] += k0 * m.z + k1 * m.w + k2 * rr;
    }

    // ---- reduction 1: min/max of conv ----
    float mn = fminf(fminf(conv[0], conv[1]), fminf(conv[2], conv[3]));
    float mx = fmaxf(fmaxf(conv[0], conv[1]), fmaxf(conv[2], conv[3]));
    butterfly32(mn, mx);
    if ((t & 31) == 0) { redA[t >> 5] = mn; redA[8 + (t >> 5)] = mx; }
    __syncthreads();
    const float cmin = fminf(fminf(fminf(redA[0], redA[1]), fminf(redA[2], redA[3])),
                             fminf(fminf(redA[4], redA[5]), fminf(redA[6], redA[7])));
    const float cmax = fmaxf(fmaxf(fmaxf(redA[8], redA[9]), fmaxf(redA[10], redA[11])),
                             fmaxf(fmaxf(redA[12], redA[13]), fmaxf(redA[14], redA[15])));

    // sharpened = x + (conv - cmin) * (255 / max(cmax-cmin, 1e-6))
    const float inv1 = 255.0f / fmaxf(cmax - cmin, 1e-6f);  // one precise div
    const float xv[4] = {x4.x, x4.y, x4.z, x4.w};
    float sh[4];
#pragma unroll
    for (int j = 0; j < 4; ++j)
        sh[j] = xv[j] + (conv[j] - cmin) * inv1;

    // ---- reduction 2: min/max of sharpened ----
    mn = fminf(fminf(sh[0], sh[1]), fminf(sh[2], sh[3]));
    mx = fmaxf(fmaxf(sh[0], sh[1]), fmaxf(sh[2], sh[3]));
    butterfly32(mn, mx);
    if ((t & 31) == 0) { redB[t >> 5] = mn; redB[8 + (t >> 5)] = mx; }
    __syncthreads();
    const float smin = fminf(fminf(fminf(redB[0], redB[1]), fminf(redB[2], redB[3])),
                             fminf(fminf(redB[4], redB[5]), fminf(redB[6], redB[7])));
    const float smax = fmaxf(fmaxf(fmaxf(redB[8], redB[9]), fmaxf(redB[10], redB[11])),
                             fmaxf(fmaxf(redB[12], redB[13]), fmaxf(redB[14], redB[15])));

    // res = floor(clip((sh - smin) * (255 / clip(smax-smin, 1e-6, 255)), 0, 255))
    const float inv2 = 255.0f / fminf(fmaxf(smax - smin, 1e-6f), 255.0f);  // one precise div
    float4 o;
    o.x = floorf(fminf(fmaxf((sh[0] - smin) * inv2, 0.0f), 255.0f));
    o.y = floorf(fminf(fmaxf((sh[1] - smin) * inv2, 0.0f), 255.0f));
    o.z = floorf(fminf(fmaxf((sh[2] - smin) * inv2, 0.0f), 255.0f));
    o.w = floorf(fminf(fmaxf((sh[3] - smin) * inv2, 0.0f), 255.0f));
    *(float4*)(dst + row * 32 + col0) = o;
}

extern "C" void kernel_launch(void* const* d_in, const int* in_sizes, int n_in,
                              void* d_out, int out_size, void* d_ws, size_t ws_size,
                              hipStream_t stream) {
    const float* in   = (const float*)d_in[0];  // (16384,1,32,32)
    const float* w    = (const float*)d_in[1];  // (1,9)
    const float* wfac = (const float*)d_in[2];  // (1,1)
    float* out = (float*)d_out;                 // (1,16384,1,32,32)
    const int B = in_sizes[0] / 1024;           // 16384
    laplacian_fwd_kernel<<<B, 256, 0, stream>>>(in, w, wfac, out);
}

// Round 3
// 117.972 us; speedup vs baseline: 1.0650x; 1.0539x over previous
//
#include <hip/hip_runtime.h>
#include <math.h>

// One block (256 threads) per 32x32 image. Thread t owns 4 consecutive
// pixels: row = t/8, cols = (t%8)*4 .. +3.
//
// Bottleneck analysis (R2): kernel was LDS-pipe-bound (~250 DS wave-insts
// per block). This version cuts DS to ~55/block:
//  - block min/max reductions via DPP (row_shr 1/2/4/8 + row_bcast 15/31)
//    in the VALU pipe; only a 1-write + 2-read LDS combine across waves.
//  - conv middle row comes from the thread's own registers; top/bottom rows
//    are 1 ds_read_b128 + 1 ds_read2_b32 each.
// LDS tile: 34 rows x stride 40, image col c at LDS col c+4 (16B-aligned
// center reads); zeroed border cells provide the conv padding.

#define S 40  // LDS row stride in floats

template <int CTRL>
__device__ __forceinline__ float dppmov(float x) {
    // old = src  =>  lanes with no valid source keep x (identity for min/max)
    return __int_as_float(__builtin_amdgcn_update_dpp(
        __float_as_int(x), __float_as_int(x), CTRL, 0xf, 0xf, false));
}

__device__ __forceinline__ void wave64_minmax(float& mn, float& mx) {
    mn = fminf(mn, dppmov<0x111>(mn)); mx = fmaxf(mx, dppmov<0x111>(mx)); // row_shr:1
    mn = fminf(mn, dppmov<0x112>(mn)); mx = fmaxf(mx, dppmov<0x112>(mx)); // row_shr:2
    mn = fminf(mn, dppmov<0x114>(mn)); mx = fmaxf(mx, dppmov<0x114>(mx)); // row_shr:4
    mn = fminf(mn, dppmov<0x118>(mn)); mx = fmaxf(mx, dppmov<0x118>(mx)); // row_shr:8
    mn = fminf(mn, dppmov<0x142>(mn)); mx = fmaxf(mx, dppmov<0x142>(mx)); // row_bcast:15
    mn = fminf(mn, dppmov<0x143>(mn)); mx = fmaxf(mx, dppmov<0x143>(mx)); // row_bcast:31
    // lane 63 now holds the wave-wide min / max
}

__global__ __launch_bounds__(256) void laplacian_fwd_kernel(
    const float* __restrict__ in,      // (16384, 1, 32, 32)
    const float* __restrict__ weight,  // (1, 9)
    const float* __restrict__ wfac,    // (1, 1)
    float* __restrict__ out)           // (1, 16384, 1, 32, 32)
{
    __shared__ float img[34 * S];
    __shared__ __align__(16) float redA[8];  // [0..3] wave mins, [4..7] wave maxs
    __shared__ __align__(16) float redB[8];

    const int b = blockIdx.x;
    const int t = threadIdx.x;
    const float* src = in + (size_t)b * 1024;
    float* dst = out + (size_t)b * 1024;

    const int row  = t >> 3;        // 0..31
    const int col0 = (t & 7) << 2;  // 0,4,...,28

    // Global load early (overlaps border zeroing / weight prep).
    const float4 x4 = *(const float4*)(src + row * 32 + col0);

    // Border zeros: LDS rows 0 and 33 (full 40-wide), LDS cols 3 and 36 for
    // rows 1..32. <=1 write per thread.
    if (t < 40)       img[t] = 0.0f;
    else if (t < 80)  img[33 * S + (t - 40)] = 0.0f;
    else if (t < 112) img[(t - 79) * S + 3]  = 0.0f;
    else if (t < 144) img[(t - 111) * S + 36] = 0.0f;

    // Kernel coefficients (block-uniform).
    const float wf = fminf(fmaxf(wfac[0], 1.001f), 254.999f);
    float k[9];
#pragma unroll
    for (int i = 0; i < 9; ++i)
        k[i] = fminf(fmaxf(weight[i], -0.999f), 0.999f) * wf;

    *(float4*)&img[(row + 1) * S + (col0 + 4)] = x4;
    __syncthreads();

    // 3x3 cross-correlation. Top/bottom rows: b128 + read2; middle row from
    // registers (own x4) + read2 for the 2 halo scalars.
    const float* pt = &img[ row      * S + col0];
    const float* pm = &img[(row + 1) * S + col0];
    const float* pb = &img[(row + 2) * S + col0];
    const float  tl = pt[3], tr = pt[8];
    const float4 tm = *(const float4*)(pt + 4);
    const float  ml = pm[3], mr = pm[8];
    const float  bl = pb[3], br = pb[8];
    const float4 bm = *(const float4*)(pb + 4);

    float conv[4];
    conv[0] = k[0]*tl   + k[1]*tm.x + k[2]*tm.y
            + k[3]*ml   + k[4]*x4.x + k[5]*x4.y
            + k[6]*bl   + k[7]*bm.x + k[8]*bm.y;
    conv[1] = k[0]*tm.x + k[1]*tm.y + k[2]*tm.z
            + k[3]*x4.x + k[4]*x4.y + k[5]*x4.z
            + k[6]*bm.x + k[7]*bm.y + k[8]*bm.z;
    conv[2] = k[0]*tm.y + k[1]*tm.z + k[2]*tm.w
            + k[3]*x4.y + k[4]*x4.z + k[5]*x4.w
            + k[6]*bm.y + k[7]*bm.z + k[8]*bm.w;
    conv[3] = k[0]*tm.z + k[1]*tm.w + k[2]*tr
            + k[3]*x4.z + k[4]*x4.w + k[5]*mr
            + k[6]*bm.z + k[7]*bm.w + k[8]*br;

    const int wv = t >> 6;

    // ---- reduction 1: min/max of conv ----
    float mn = fminf(fminf(conv[0], conv[1]), fminf(conv[2], conv[3]));
    float mx = fmaxf(fmaxf(conv[0], conv[1]), fmaxf(conv[2], conv[3]));
    wave64_minmax(mn, mx);
    if ((t & 63) == 63) { redA[wv] = mn; redA[4 + wv] = mx; }
    __syncthreads();
    const float4 amn = *(const float4*)&redA[0];
    const float4 amx = *(const float4*)&redA[4];
    const float cmin = fminf(fminf(amn.x, amn.y), fminf(amn.z, amn.w));
    const float cmax = fmaxf(fmaxf(amx.x, amx.y), fmaxf(amx.z, amx.w));

    // sharpened = x + (conv - cmin) * (255 / max(cmax-cmin, 1e-6))
    const float inv1 = 255.0f / fmaxf(cmax - cmin, 1e-6f);  // one precise div
    const float xv[4] = {x4.x, x4.y, x4.z, x4.w};
    float sh[4];
#pragma unroll
    for (int j = 0; j < 4; ++j)
        sh[j] = xv[j] + (conv[j] - cmin) * inv1;

    // ---- reduction 2: min/max of sharpened ----
    mn = fminf(fminf(sh[0], sh[1]), fminf(sh[2], sh[3]));
    mx = fmaxf(fmaxf(sh[0], sh[1]), fmaxf(sh[2], sh[3]));
    wave64_minmax(mn, mx);
    if ((t & 63) == 63) { redB[wv] = mn; redB[4 + wv] = mx; }
    __syncthreads();
    const float4 bmn = *(const float4*)&redB[0];
    const float4 bmx = *(const float4*)&redB[4];
    const float smin = fminf(fminf(bmn.x, bmn.y), fminf(bmn.z, bmn.w));
    const float smax = fmaxf(fmaxf(bmx.x, bmx.y), fmaxf(bmx.z, bmx.w));

    // res = floor(clip((sh - smin) * (255 / clip(smax-smin, 1e-6, 255)), 0, 255))
    const float inv2 = 255.0f / fminf(fmaxf(smax - smin, 1e-6f), 255.0f);  // one precise div
    float4 o;
    o.x = floorf(fminf(fmaxf((sh[0] - smin) * inv2, 0.0f), 255.0f));
    o.y = floorf(fminf(fmaxf((sh[1] - smin) * inv2, 0.0f), 255.0f));
    o.z = floorf(fminf(fmaxf((sh[2] - smin) * inv2, 0.0f), 255.0f));
    o.w = floorf(fminf(fmaxf((sh[3] - smin) * inv2, 0.0f), 255.0f));
    *(float4*)(dst + row * 32 + col0) = o;
}

extern "C" void kernel_launch(void* const* d_in, const int* in_sizes, int n_in,
                              void* d_out, int out_size, void* d_ws, size_t ws_size,
                              hipStream_t stream) {
    const float* in   = (const float*)d_in[0];  // (16384,1,32,32)
    const float* w    = (const float*)d_in[1];  // (1,9)
    const float* wfac = (const float*)d_in[2];  // (1,1)
    float* out = (float*)d_out;                 // (1,16384,1,32,32)
    const int B = in_sizes[0] / 1024;           // 16384
    laplacian_fwd_kernel<<<B, 256, 0, stream>>>(in, w, wfac, out);
}

// Round 4
// 112.008 us; speedup vs baseline: 1.1218x; 1.0533x over previous
//
#include <hip/hip_runtime.h>
#include <math.h>

// One 64-thread block (= ONE wave) per 32x32 image, 16 px/thread.
// Thread t owns rows {8i + t/8 : i=0..3}, cols (t%8)*4 .. +3 (4 float4s).
// Single-wave block => __syncthreads() has no cross-wave stall (compiler
// elides s_barrier for workgroup <= wavesize); block reductions are pure
// DPP + readlane broadcast — zero LDS combine, zero barrier convoys.
// LDS tile: 34 rows x stride 40, image col c at LDS col c+4 (16B-aligned
// b128 center reads); zeroed border provides conv padding.

#define S 40  // LDS row stride in floats

template <int CTRL>
__device__ __forceinline__ float dppmov(float x) {
    // old = src  =>  lanes with no valid source keep x (identity for min/max)
    return __int_as_float(__builtin_amdgcn_update_dpp(
        __float_as_int(x), __float_as_int(x), CTRL, 0xf, 0xf, false));
}

__device__ __forceinline__ void wave64_minmax(float& mn, float& mx) {
    mn = fminf(mn, dppmov<0x111>(mn)); mx = fmaxf(mx, dppmov<0x111>(mx)); // row_shr:1
    mn = fminf(mn, dppmov<0x112>(mn)); mx = fmaxf(mx, dppmov<0x112>(mx)); // row_shr:2
    mn = fminf(mn, dppmov<0x114>(mn)); mx = fmaxf(mx, dppmov<0x114>(mx)); // row_shr:4
    mn = fminf(mn, dppmov<0x118>(mn)); mx = fmaxf(mx, dppmov<0x118>(mx)); // row_shr:8
    mn = fminf(mn, dppmov<0x142>(mn)); mx = fmaxf(mx, dppmov<0x142>(mx)); // row_bcast:15
    mn = fminf(mn, dppmov<0x143>(mn)); mx = fmaxf(mx, dppmov<0x143>(mx)); // row_bcast:31
    // lane 63 holds the wave-wide min / max
}

__global__ __launch_bounds__(64) void laplacian_fwd_kernel(
    const float* __restrict__ in,      // (16384, 1, 32, 32)
    const float* __restrict__ weight,  // (1, 9)
    const float* __restrict__ wfac,    // (1, 1)
    float* __restrict__ out)           // (1, 16384, 1, 32, 32)
{
    __shared__ float img[34 * S];

    const int b = blockIdx.x;
    const int t = threadIdx.x;  // 0..63
    const float* src = in + (size_t)b * 1024;
    float* dst = out + (size_t)b * 1024;

    const int rbase = t >> 3;       // 0..7  (row within each 8-row chunk)
    const int col0  = (t & 7) << 2; // 0,4,...,28

    // 4 independent coalesced float4 loads (issue early, overlap latency).
    float4 x4[4];
#pragma unroll
    for (int i = 0; i < 4; ++i)
        x4[i] = *(const float4*)(src + i * 256 + t * 4);

    // Border zeros: LDS rows 0 and 33 (full 40-wide), LDS cols 3 and 36 for
    // rows 1..32.
    if (t < 40) { img[t] = 0.0f; img[33 * S + t] = 0.0f; }
    if (t < 32) { img[(t + 1) * S + 3] = 0.0f; img[(t + 1) * S + 36] = 0.0f; }

    // Kernel coefficients (uniform).
    const float wf = fminf(fmaxf(wfac[0], 1.001f), 254.999f);
    float k[9];
#pragma unroll
    for (int i = 0; i < 9; ++i)
        k[i] = fminf(fmaxf(weight[i], -0.999f), 0.999f) * wf;

    // Stage 4 rows into LDS.
#pragma unroll
    for (int i = 0; i < 4; ++i)
        *(float4*)&img[(i * 8 + rbase + 1) * S + (col0 + 4)] = x4[i];
    __syncthreads();  // single-wave: ordering only, no cross-wave stall

    // 3x3 cross-correlation; middle-row center from registers.
    float conv[4][4];
#pragma unroll
    for (int i = 0; i < 4; ++i) {
        const int row = i * 8 + rbase;
        const float* pt = &img[ row      * S + col0];
        const float* pm = &img[(row + 1) * S + col0];
        const float* pb = &img[(row + 2) * S + col0];
        const float  tl = pt[3], tr = pt[8];
        const float4 tm = *(const float4*)(pt + 4);
        const float  ml = pm[3], mr = pm[8];
        const float  bl = pb[3], br = pb[8];
        const float4 bm = *(const float4*)(pb + 4);
        const float4 m  = x4[i];
        conv[i][0] = k[0]*tl   + k[1]*tm.x + k[2]*tm.y
                   + k[3]*ml   + k[4]*m.x  + k[5]*m.y
                   + k[6]*bl   + k[7]*bm.x + k[8]*bm.y;
        conv[i][1] = k[0]*tm.x + k[1]*tm.y + k[2]*tm.z
                   + k[3]*m.x  + k[4]*m.y  + k[5]*m.z
                   + k[6]*bm.x + k[7]*bm.y + k[8]*bm.z;
        conv[i][2] = k[0]*tm.y + k[1]*tm.z + k[2]*tm.w
                   + k[3]*m.y  + k[4]*m.z  + k[5]*m.w
                   + k[6]*bm.y + k[7]*bm.z + k[8]*bm.w;
        conv[i][3] = k[0]*tm.z + k[1]*tm.w + k[2]*tr
                   + k[3]*m.z  + k[4]*m.w  + k[5]*mr
                   + k[6]*bm.z + k[7]*bm.w + k[8]*br;
    }

    // ---- reduction 1: min/max of conv over the image (pure DPP) ----
    float mn = conv[0][0], mx = conv[0][0];
#pragma unroll
    for (int i = 0; i < 4; ++i)
#pragma unroll
        for (int j = 0; j < 4; ++j) {
            mn = fminf(mn, conv[i][j]);
            mx = fmaxf(mx, conv[i][j]);
        }
    wave64_minmax(mn, mx);
    const float cmin = __builtin_amdgcn_readlane(__float_as_int(mn), 63) == 0
                       ? __int_as_float(__builtin_amdgcn_readlane(__float_as_int(mn), 63))
                       : __int_as_float(__builtin_amdgcn_readlane(__float_as_int(mn), 63));
    const float cmax = __int_as_float(__builtin_amdgcn_readlane(__float_as_int(mx), 63));

    // sharpened = x + (conv - cmin) * (255 / max(cmax-cmin, 1e-6))
    const float inv1 = 255.0f / fmaxf(cmax - cmin, 1e-6f);  // one precise div
    float sh[4][4];
#pragma unroll
    for (int i = 0; i < 4; ++i) {
        sh[i][0] = x4[i].x + (conv[i][0] - cmin) * inv1;
        sh[i][1] = x4[i].y + (conv[i][1] - cmin) * inv1;
        sh[i][2] = x4[i].z + (conv[i][2] - cmin) * inv1;
        sh[i][3] = x4[i].w + (conv[i][3] - cmin) * inv1;
    }

    // ---- reduction 2: min/max of sharpened ----
    mn = sh[0][0]; mx = sh[0][0];
#pragma unroll
    for (int i = 0; i < 4; ++i)
#pragma unroll
        for (int j = 0; j < 4; ++j) {
            mn = fminf(mn, sh[i][j]);
            mx = fmaxf(mx, sh[i][j]);
        }
    wave64_minmax(mn, mx);
    const float smin = __int_as_float(__builtin_amdgcn_readlane(__float_as_int(mn), 63));
    const float smax = __int_as_float(__builtin_amdgcn_readlane(__float_as_int(mx), 63));

    // res = floor(clip((sh - smin) * (255 / clip(smax-smin, 1e-6, 255)), 0, 255))
    const float inv2 = 255.0f / fminf(fmaxf(smax - smin, 1e-6f), 255.0f);  // one precise div
#pragma unroll
    for (int i = 0; i < 4; ++i) {
        float4 o;
        o.x = floorf(fminf(fmaxf((sh[i][0] - smin) * inv2, 0.0f), 255.0f));
        o.y = floorf(fminf(fmaxf((sh[i][1] - smin) * inv2, 0.0f), 255.0f));
        o.z = floorf(fminf(fmaxf((sh[i][2] - smin) * inv2, 0.0f), 255.0f));
        o.w = floorf(fminf(fmaxf((sh[i][3] - smin) * inv2, 0.0f), 255.0f));
        *(float4*)(dst + i * 256 + t * 4) = o;
    }
}

extern "C" void kernel_launch(void* const* d_in, const int* in_sizes, int n_in,
                              void* d_out, int out_size, void* d_ws, size_t ws_size,
                              hipStream_t stream) {
    const float* in   = (const float*)d_in[0];  // (16384,1,32,32)
    const float* w    = (const float*)d_in[1];  // (1,9)
    const float* wfac = (const float*)d_in[2];  // (1,1)
    float* out = (float*)d_out;                 // (1,16384,1,32,32)
    const int B = in_sizes[0] / 1024;           // 16384
    laplacian_fwd_kernel<<<B, 64, 0, stream>>>(in, w, wfac, out);
}

// Round 6
// 111.677 us; speedup vs baseline: 1.1251x; 1.0030x over previous
//
#include <hip/hip_runtime.h>
#include <math.h>

// Grid 2048 x 256. Each block = 4 independent waves; each wave processes 2
// consecutive 32x32 images (16 px/thread) with register prefetch of image 1
// issued before image 0's compute. NO __syncthreads: waves use disjoint LDS
// slices; within a wave the LDS pipe is in-order, and
// __builtin_amdgcn_wave_barrier() fences compiler reordering.
//
// LDS slice per wave: 34 rows x stride 36 + 4-float pad = 1228 floats.
// Image col c -> LDS col c+4 (16B-aligned b128 center reads). Left halo at
// col 3; right halo reads land at (row+1)*36 col 0 (zeroed) or the pad.
// Borders zeroed once per wave, reused for both images (image stores only
// touch rows 1..32, cols 4..35).

#define S 36
#define SLICE 1228  // 34*36 + 4 pad

typedef float floatx4 __attribute__((ext_vector_type(4)));

template <int CTRL>
__device__ __forceinline__ float dppmov(float x) {
    // old = src => bound lanes keep x (identity for min/max)
    return __int_as_float(__builtin_amdgcn_update_dpp(
        __float_as_int(x), __float_as_int(x), CTRL, 0xf, 0xf, false));
}

__device__ __forceinline__ void wave64_minmax(float& mn, float& mx) {
    mn = fminf(mn, dppmov<0x111>(mn)); mx = fmaxf(mx, dppmov<0x111>(mx)); // row_shr:1
    mn = fminf(mn, dppmov<0x112>(mn)); mx = fmaxf(mx, dppmov<0x112>(mx)); // row_shr:2
    mn = fminf(mn, dppmov<0x114>(mn)); mx = fmaxf(mx, dppmov<0x114>(mx)); // row_shr:4
    mn = fminf(mn, dppmov<0x118>(mn)); mx = fmaxf(mx, dppmov<0x118>(mx)); // row_shr:8
    mn = fminf(mn, dppmov<0x142>(mn)); mx = fmaxf(mx, dppmov<0x142>(mx)); // row_bcast:15
    mn = fminf(mn, dppmov<0x143>(mn)); mx = fmaxf(mx, dppmov<0x143>(mx)); // row_bcast:31
    // lane 63 holds the wave-wide min / max
}

__device__ __forceinline__ void process_image(
    float* __restrict__ sm, const float4* x4, const float* k,
    float* __restrict__ dst, int lane)
{
    const int rbase = lane >> 3;        // 0..7
    const int col0  = (lane & 7) << 2;  // 0,4,...,28

    // Stage 4 rows (fence: don't hoist these writes above the previous
    // image's LDS reads; LDS pipe is in-order within a wave).
    __builtin_amdgcn_wave_barrier();
#pragma unroll
    for (int i = 0; i < 4; ++i)
        *(float4*)&sm[(i * 8 + rbase + 1) * S + (col0 + 4)] = x4[i];
    __builtin_amdgcn_wave_barrier();

    // 3x3 cross-correlation; middle-row center from registers.
    float conv[4][4];
#pragma unroll
    for (int i = 0; i < 4; ++i) {
        const int row = i * 8 + rbase;          // image row
        const float* pt = &sm[ row      * S + col0];
        const float* pm = &sm[(row + 1) * S + col0];
        const float* pb = &sm[(row + 2) * S + col0];
        const float  tl = pt[3], tr = pt[8];
        const float4 tm = *(const float4*)(pt + 4);
        const float  ml = pm[3], mr = pm[8];
        const float  bl = pb[3], br = pb[8];
        const float4 bm = *(const float4*)(pb + 4);
        const float4 m  = x4[i];
        conv[i][0] = k[0]*tl   + k[1]*tm.x + k[2]*tm.y
                   + k[3]*ml   + k[4]*m.x  + k[5]*m.y
                   + k[6]*bl   + k[7]*bm.x + k[8]*bm.y;
        conv[i][1] = k[0]*tm.x + k[1]*tm.y + k[2]*tm.z
                   + k[3]*m.x  + k[4]*m.y  + k[5]*m.z
                   + k[6]*bm.x + k[7]*bm.y + k[8]*bm.z;
        conv[i][2] = k[0]*tm.y + k[1]*tm.z + k[2]*tm.w
                   + k[3]*m.y  + k[4]*m.z  + k[5]*m.w
                   + k[6]*bm.y + k[7]*bm.z + k[8]*bm.w;
        conv[i][3] = k[0]*tm.z + k[1]*tm.w + k[2]*tr
                   + k[3]*m.z  + k[4]*m.w  + k[5]*mr
                   + k[6]*bm.z + k[7]*bm.w + k[8]*br;
    }
    __builtin_amdgcn_wave_barrier();

    // ---- reduction 1: min/max of conv (pure DPP) ----
    float mn = conv[0][0], mx = conv[0][0];
#pragma unroll
    for (int i = 0; i < 4; ++i)
#pragma unroll
        for (int j = 0; j < 4; ++j) {
            mn = fminf(mn, conv[i][j]);
            mx = fmaxf(mx, conv[i][j]);
        }
    wave64_minmax(mn, mx);
    const float cmin = __int_as_float(__builtin_amdgcn_readlane(__float_as_int(mn), 63));
    const float cmax = __int_as_float(__builtin_amdgcn_readlane(__float_as_int(mx), 63));

    // sharpened = x + (conv - cmin) * (255 / max(cmax-cmin, 1e-6))
    const float inv1 = 255.0f / fmaxf(cmax - cmin, 1e-6f);
    float sh[4][4];
#pragma unroll
    for (int i = 0; i < 4; ++i) {
        sh[i][0] = x4[i].x + (conv[i][0] - cmin) * inv1;
        sh[i][1] = x4[i].y + (conv[i][1] - cmin) * inv1;
        sh[i][2] = x4[i].z + (conv[i][2] - cmin) * inv1;
        sh[i][3] = x4[i].w + (conv[i][3] - cmin) * inv1;
    }

    // ---- reduction 2: min/max of sharpened ----
    mn = sh[0][0]; mx = sh[0][0];
#pragma unroll
    for (int i = 0; i < 4; ++i)
#pragma unroll
        for (int j = 0; j < 4; ++j) {
            mn = fminf(mn, sh[i][j]);
            mx = fmaxf(mx, sh[i][j]);
        }
    wave64_minmax(mn, mx);
    const float smin = __int_as_float(__builtin_amdgcn_readlane(__float_as_int(mn), 63));
    const float smax = __int_as_float(__builtin_amdgcn_readlane(__float_as_int(mx), 63));

    // res = floor(clip((sh - smin) * (255 / clip(smax-smin, 1e-6, 255)), 0, 255))
    const float inv2 = 255.0f / fminf(fmaxf(smax - smin, 1e-6f), 255.0f);
#pragma unroll
    for (int i = 0; i < 4; ++i) {
        floatx4 o;
        o.x = floorf(fminf(fmaxf((sh[i][0] - smin) * inv2, 0.0f), 255.0f));
        o.y = floorf(fminf(fmaxf((sh[i][1] - smin) * inv2, 0.0f), 255.0f));
        o.z = floorf(fminf(fmaxf((sh[i][2] - smin) * inv2, 0.0f), 255.0f));
        o.w = floorf(fminf(fmaxf((sh[i][3] - smin) * inv2, 0.0f), 255.0f));
        __builtin_nontemporal_store(o, (floatx4*)(dst + i * 256 + lane * 4));
    }
}

__global__ __launch_bounds__(256) void laplacian_fwd_kernel(
    const float* __restrict__ in,      // (16384, 1, 32, 32)
    const float* __restrict__ weight,  // (1, 9)
    const float* __restrict__ wfac,    // (1, 1)
    float* __restrict__ out)           // (1, 16384, 1, 32, 32)
{
    __shared__ float lds[4 * SLICE];

    const int t    = threadIdx.x;
    const int w    = t >> 6;   // wave in block
    const int lane = t & 63;
    float* sm = &lds[w * SLICE];

    const int W = blockIdx.x * 4 + w;            // 0..8191
    const size_t base0 = (size_t)(2 * W) * 1024; // two consecutive images
    const size_t base1 = base0 + 1024;

    // Issue image-0 loads immediately.
    float4 xa[4];
#pragma unroll
    for (int i = 0; i < 4; ++i)
        xa[i] = *(const float4*)(in + base0 + i * 256 + lane * 4);

    // Border zeros (once per wave; persist for both images).
    // Row 0 and row 33 full width; col 0 and col 3 for rows 1..32; pad.
    if (lane < 36) { sm[lane] = 0.0f; sm[33 * S + lane] = 0.0f; }
    if (lane < 32) { sm[(lane + 1) * S] = 0.0f; sm[(lane + 1) * S + 3] = 0.0f; }
    if (lane == 0) sm[34 * S] = 0.0f;  // pad: right-halo read of LDS row 33

    // Kernel coefficients (uniform).
    const float wf = fminf(fmaxf(wfac[0], 1.001f), 254.999f);
    float k[9];
#pragma unroll
    for (int i = 0; i < 9; ++i)
        k[i] = fminf(fmaxf(weight[i], -0.999f), 0.999f) * wf;

    // Prefetch image-1 loads before image-0 compute.
    float4 xb[4];
#pragma unroll
    for (int i = 0; i < 4; ++i)
        xb[i] = *(const float4*)(in + base1 + i * 256 + lane * 4);

    process_image(sm, xa, k, out + base0, lane);
    process_image(sm, xb, k, out + base1, lane);
}

extern "C" void kernel_launch(void* const* d_in, const int* in_sizes, int n_in,
                              void* d_out, int out_size, void* d_ws, size_t ws_size,
                              hipStream_t stream) {
    const float* in   = (const float*)d_in[0];  // (16384,1,32,32)
    const float* w    = (const float*)d_in[1];  // (1,9)
    const float* wfac = (const float*)d_in[2];  // (1,1)
    float* out = (float*)d_out;                 // (1,16384,1,32,32)
    const int B = in_sizes[0] / 1024;           // 16384
    const int nblocks = B / 8;                  // 4 waves x 2 images each
    laplacian_fwd_kernel<<<nblocks, 256, 0, stream>>>(in, w, wfac, out);
}

// Round 7
// 109.871 us; speedup vs baseline: 1.1436x; 1.0164x over previous
//
#include <hip/hip_runtime.h>
#include <math.h>

// Grid 2048 x 256. Each block = 4 independent waves; each wave processes 2
// consecutive 32x32 images (16 px/thread), image-1 loads prefetched before
// image-0 compute. No __syncthreads: waves use disjoint LDS slices; LDS pipe
// is in-order within a wave; __builtin_amdgcn_wave_barrier() fences the
// compiler.
//
// FAST PATH (taken when all 8 neighbor weights are equal — true for the
// Laplacian input): conv = k0*sum9 + (k4-k0)*x, sum9 via separable rowsums.
//  - horizontal rowsums in registers; left/right neighbor pixels come from
//    zero-fill wave-DPP shifts (no raw-pixel LDS, no column borders);
//  - rowsums staged to LDS (4 ds_write_b128), vertical sum = 2 ds_read_b128
//    per chunk (top/bottom) + own rowsum from registers.
// Generic fallback: raw 9-fma conv via LDS tile (R6 structure).
// LDS slice/wave: 34 rows x stride 36 + pad = 1228 floats; data at col+4
// (16B-aligned b128); rows 0/33 zeroed (vertical padding), cols 0,3 zeroed
// for the generic path's halo.

#define S 36
#define SLICE 1228

typedef float floatx4 __attribute__((ext_vector_type(4)));

template <int CTRL>
__device__ __forceinline__ float dppmov(float x) {
    // old = src => bound lanes keep x (identity for min/max)
    return __int_as_float(__builtin_amdgcn_update_dpp(
        __float_as_int(x), __float_as_int(x), CTRL, 0xf, 0xf, false));
}

template <int CTRL>
__device__ __forceinline__ float dppsh0(float x) {
    // zero-fill shift: old = 0, bound_ctrl = true
    return __int_as_float(__builtin_amdgcn_update_dpp(
        0, __float_as_int(x), CTRL, 0xf, 0xf, true));
}

__device__ __forceinline__ void wave64_minmax(float& mn, float& mx) {
    mn = fminf(mn, dppmov<0x111>(mn)); mx = fmaxf(mx, dppmov<0x111>(mx)); // row_shr:1
    mn = fminf(mn, dppmov<0x112>(mn)); mx = fmaxf(mx, dppmov<0x112>(mx)); // row_shr:2
    mn = fminf(mn, dppmov<0x114>(mn)); mx = fmaxf(mx, dppmov<0x114>(mx)); // row_shr:4
    mn = fminf(mn, dppmov<0x118>(mn)); mx = fmaxf(mx, dppmov<0x118>(mx)); // row_shr:8
    mn = fminf(mn, dppmov<0x142>(mn)); mx = fmaxf(mx, dppmov<0x142>(mx)); // row_bcast:15
    mn = fminf(mn, dppmov<0x143>(mn)); mx = fmaxf(mx, dppmov<0x143>(mx)); // row_bcast:31
    // lane 63 holds the wave-wide min / max
}

// Reductions + normalize + clip + floor + store (shared by both paths).
__device__ __forceinline__ void finish_image(
    const float4* __restrict__ x4, float conv[4][4],
    float* __restrict__ dst, int lane)
{
    // ---- reduction 1: min/max of conv ----
    float mn = conv[0][0], mx = conv[0][0];
#pragma unroll
    for (int i = 0; i < 4; ++i)
#pragma unroll
        for (int j = 0; j < 4; ++j) {
            mn = fminf(mn, conv[i][j]);
            mx = fmaxf(mx, conv[i][j]);
        }
    wave64_minmax(mn, mx);
    const float cmin = __int_as_float(__builtin_amdgcn_readlane(__float_as_int(mn), 63));
    const float cmax = __int_as_float(__builtin_amdgcn_readlane(__float_as_int(mx), 63));

    const float inv1 = 255.0f / fmaxf(cmax - cmin, 1e-6f);
    float sh[4][4];
#pragma unroll
    for (int i = 0; i < 4; ++i) {
        sh[i][0] = x4[i].x + (conv[i][0] - cmin) * inv1;
        sh[i][1] = x4[i].y + (conv[i][1] - cmin) * inv1;
        sh[i][2] = x4[i].z + (conv[i][2] - cmin) * inv1;
        sh[i][3] = x4[i].w + (conv[i][3] - cmin) * inv1;
    }

    // ---- reduction 2: min/max of sharpened ----
    mn = sh[0][0]; mx = sh[0][0];
#pragma unroll
    for (int i = 0; i < 4; ++i)
#pragma unroll
        for (int j = 0; j < 4; ++j) {
            mn = fminf(mn, sh[i][j]);
            mx = fmaxf(mx, sh[i][j]);
        }
    wave64_minmax(mn, mx);
    const float smin = __int_as_float(__builtin_amdgcn_readlane(__float_as_int(mn), 63));
    const float smax = __int_as_float(__builtin_amdgcn_readlane(__float_as_int(mx), 63));

    // res = floor(clip(sh*inv2 + c2, 0, 255)),  c2 = -smin*inv2 (uniform)
    const float inv2 = 255.0f / fminf(fmaxf(smax - smin, 1e-6f), 255.0f);
    const float c2 = -smin * inv2;
#pragma unroll
    for (int i = 0; i < 4; ++i) {
        floatx4 o;
        o.x = floorf(fminf(fmaxf(sh[i][0] * inv2 + c2, 0.0f), 255.0f));
        o.y = floorf(fminf(fmaxf(sh[i][1] * inv2 + c2, 0.0f), 255.0f));
        o.z = floorf(fminf(fmaxf(sh[i][2] * inv2 + c2, 0.0f), 255.0f));
        o.w = floorf(fminf(fmaxf(sh[i][3] * inv2 + c2, 0.0f), 255.0f));
        __builtin_nontemporal_store(o, (floatx4*)(dst + i * 256 + lane * 4));
    }
}

// Fast path: all 8 neighbor coefficients equal k0, center k4.
__device__ __forceinline__ void process_image_fast(
    float* __restrict__ sm, const float4* __restrict__ x4,
    float k0, float dk, float* __restrict__ dst, int lane)
{
    const int rbase = lane >> 3;        // 0..7
    const int col0  = (lane & 7) << 2;  // 0,4,...,28
    const bool ledge = (lane & 7) == 0;
    const bool redge = (lane & 7) == 7;

    float4 rs[4];  // horizontal rowsums of own rows
    __builtin_amdgcn_wave_barrier();
#pragma unroll
    for (int i = 0; i < 4; ++i) {
        const float4 m = x4[i];
        float lv = dppsh0<0x138>(m.w);  // wave_shr:1 -> lane-1's m.w
        float rv = dppsh0<0x130>(m.x);  // wave_shl:1 -> lane+1's m.x
        lv = ledge ? 0.0f : lv;
        rv = redge ? 0.0f : rv;
        const float t1 = m.x + m.y;
        const float t2 = m.z + m.w;
        rs[i].x = lv + t1;
        rs[i].y = t1 + m.z;
        rs[i].z = m.y + t2;
        rs[i].w = t2 + rv;
        *(float4*)&sm[(i * 8 + rbase + 1) * S + (col0 + 4)] = rs[i];
    }
    __builtin_amdgcn_wave_barrier();

    float conv[4][4];
#pragma unroll
    for (int i = 0; i < 4; ++i) {
        const int row = i * 8 + rbase;  // image row
        const float4 top = *(const float4*)&sm[ row      * S + col0 + 4];
        const float4 bot = *(const float4*)&sm[(row + 2) * S + col0 + 4];
        conv[i][0] = (top.x + rs[i].x + bot.x) * k0 + dk * x4[i].x;
        conv[i][1] = (top.y + rs[i].y + bot.y) * k0 + dk * x4[i].y;
        conv[i][2] = (top.z + rs[i].z + bot.z) * k0 + dk * x4[i].z;
        conv[i][3] = (top.w + rs[i].w + bot.w) * k0 + dk * x4[i].w;
    }
    __builtin_amdgcn_wave_barrier();

    finish_image(x4, conv, dst, lane);
}

// Generic fallback: raw pixels in LDS, 9-fma conv (R6 structure).
__device__ __forceinline__ void process_image_gen(
    float* __restrict__ sm, const float4* __restrict__ x4, const float* k,
    float* __restrict__ dst, int lane)
{
    const int rbase = lane >> 3;
    const int col0  = (lane & 7) << 2;

    __builtin_amdgcn_wave_barrier();
#pragma unroll
    for (int i = 0; i < 4; ++i)
        *(float4*)&sm[(i * 8 + rbase + 1) * S + (col0 + 4)] = x4[i];
    __builtin_amdgcn_wave_barrier();

    float conv[4][4];
#pragma unroll
    for (int i = 0; i < 4; ++i) {
        const int row = i * 8 + rbase;
        const float* pt = &sm[ row      * S + col0];
        const float* pm = &sm[(row + 1) * S + col0];
        const float* pb = &sm[(row + 2) * S + col0];
        const float  tl = pt[3], tr = pt[8];
        const float4 tm = *(const float4*)(pt + 4);
        const float  ml = pm[3], mr = pm[8];
        const float  bl = pb[3], br = pb[8];
        const float4 bm = *(const float4*)(pb + 4);
        const float4 m  = x4[i];
        conv[i][0] = k[0]*tl   + k[1]*tm.x + k[2]*tm.y
                   + k[3]*ml   + k[4]*m.x  + k[5]*m.y
                   + k[6]*bl   + k[7]*bm.x + k[8]*bm.y;
        conv[i][1] = k[0]*tm.x + k[1]*tm.y + k[2]*tm.z
                   + k[3]*m.x  + k[4]*m.y  + k[5]*m.z
                   + k[6]*bm.x + k[7]*bm.y + k[8]*bm.z;
        conv[i][2] = k[0]*tm.y + k[1]*tm.z + k[2]*tm.w
                   + k[3]*m.y  + k[4]*m.z  + k[5]*m.w
                   + k[6]*bm.y + k[7]*bm.z + k[8]*bm.w;
        conv[i][3] = k[0]*tm.z + k[1]*tm.w + k[2]*tr
                   + k[3]*m.z  + k[4]*m.w  + k[5]*mr
                   + k[6]*bm.z + k[7]*bm.w + k[8]*br;
    }
    __builtin_amdgcn_wave_barrier();

    finish_image(x4, conv, dst, lane);
}

__global__ __launch_bounds__(256) void laplacian_fwd_kernel(
    const float* __restrict__ in,      // (16384, 1, 32, 32)
    const float* __restrict__ weight,  // (1, 9)
    const float* __restrict__ wfac,    // (1, 1)
    float* __restrict__ out)           // (1, 16384, 1, 32, 32)
{
    __shared__ float lds[4 * SLICE];

    const int t    = threadIdx.x;
    const int w    = t >> 6;
    const int lane = t & 63;
    float* sm = &lds[w * SLICE];

    const int W = blockIdx.x * 4 + w;            // 0..8191
    const size_t base0 = (size_t)(2 * W) * 1024;
    const size_t base1 = base0 + 1024;

    // Issue image-0 loads immediately.
    float4 xa[4];
#pragma unroll
    for (int i = 0; i < 4; ++i)
        xa[i] = *(const float4*)(in + base0 + i * 256 + lane * 4);

    // Border zeros (persist for both images / both paths):
    // rows 0,33 full width; generic-path column halos at cols 0,3; pad.
    if (lane < 36) { sm[lane] = 0.0f; sm[33 * S + lane] = 0.0f; }
    if (lane < 32) { sm[(lane + 1) * S] = 0.0f; sm[(lane + 1) * S + 3] = 0.0f; }
    if (lane == 0) sm[34 * S] = 0.0f;

    // Kernel coefficients (uniform).
    const float wf = fminf(fmaxf(wfac[0], 1.001f), 254.999f);
    float k[9];
#pragma unroll
    for (int i = 0; i < 9; ++i)
        k[i] = fminf(fmaxf(weight[i], -0.999f), 0.999f) * wf;

    // Prefetch image-1 loads before image-0 compute.
    float4 xb[4];
#pragma unroll
    for (int i = 0; i < 4; ++i)
        xb[i] = *(const float4*)(in + base1 + i * 256 + lane * 4);

    // Wave-uniform specialization: all 8 neighbor coefficients equal?
    const bool fast = (k[0] == k[1]) && (k[0] == k[2]) && (k[0] == k[3]) &&
                      (k[0] == k[5]) && (k[0] == k[6]) && (k[0] == k[7]) &&
                      (k[0] == k[8]);
    if (fast) {
        const float dk = k[4] - k[0];
        process_image_fast(sm, xa, k[0], dk, out + base0, lane);
        process_image_fast(sm, xb, k[0], dk, out + base1, lane);
    } else {
        process_image_gen(sm, xa, k, out + base0, lane);
        process_image_gen(sm, xb, k, out + base1, lane);
    }
}

extern "C" void kernel_launch(void* const* d_in, const int* in_sizes, int n_in,
                              void* d_out, int out_size, void* d_ws, size_t ws_size,
                              hipStream_t stream) {
    const float* in   = (const float*)d_in[0];  // (16384,1,32,32)
    const float* w    = (const float*)d_in[1];  // (1,9)
    const float* wfac = (const float*)d_in[2];  // (1,1)
    float* out = (float*)d_out;                 // (1,16384,1,32,32)
    const int B = in_sizes[0] / 1024;           // 16384
    const int nblocks = B / 8;                  // 4 waves x 2 images each
    laplacian_fwd_kernel<<<nblocks, 256, 0, stream>>>(in, w, wfac, out);
}